// Round 5
// baseline (268.078 us; speedup 1.0000x reference)
//
#include <hip/hip_runtime.h>
#include <hip/hip_bf16.h>

#define HEADS 8
#define HID   64
#define EMB   512
#define HH    512
#define LOCAL 64
#define BS    4
#define NSEQ  2048
#define ROWS  (BS*NSEQ)   // 8192

typedef __attribute__((ext_vector_type(8))) short short8;   // 8 bf16 = 4 VGPRs
typedef __attribute__((ext_vector_type(4))) float f32x4;

// fp32 -> bf16 bits (RNE)
__device__ __forceinline__ ushort f2b(float f) {
    union { float f; unsigned u; } c; c.f = f;
    return (ushort)((c.u + 0x7FFFu + ((c.u >> 16) & 1u)) >> 16);
}
// bf16 bits -> fp32
__device__ __forceinline__ float b2f(ushort u) {
    union { unsigned u; float f; } c; c.u = ((unsigned)u) << 16; return c.f;
}
__device__ __forceinline__ float b2fs(short s) { return b2f((ushort)s); }

// async global->LDS, 16B per lane; LDS layout MUST be base + lane*16.
__device__ __forceinline__ void async16(const void* g, void* l) {
    __builtin_amdgcn_global_load_lds(
        (const __attribute__((address_space(1))) void*)g,
        (__attribute__((address_space(3))) void*)l, 16, 0, 0);
}

// ---------------------------------------------------------------------------
// x -> bf16 (vectorized)
// ---------------------------------------------------------------------------
__global__ __launch_bounds__(256) void f2b_vec(const float* __restrict__ in,
                                               ushort* __restrict__ out, int n4) {
    int i = blockIdx.x * 256 + threadIdx.x;
    if (i >= n4) return;
    float4 f = ((const float4*)in)[i];
    ushort4 u;
    u.x = f2b(f.x); u.y = f2b(f.y); u.z = f2b(f.z); u.w = f2b(f.w);
    ((ushort4*)out)[i] = u;
}

// all 4 weight transposes in one launch: z=0..2 -> wq/wk/wv into dst012,
// z=3 -> wu into dst3.  out[n][k] = bf16(in[k][n])
__global__ __launch_bounds__(256) void transpose_f2b4(
    const float* __restrict__ w0, const float* __restrict__ w1,
    const float* __restrict__ w2, const float* __restrict__ w3,
    ushort* __restrict__ dst012, ushort* __restrict__ dst3)
{
    __shared__ float s[16][17];
    const int z = blockIdx.z;
    const float* src = (z == 0) ? w0 : (z == 1) ? w1 : (z == 2) ? w2 : w3;
    ushort* dst = (z < 3) ? dst012 + (size_t)z * 512 * 512 : dst3;
    const int k0 = blockIdx.y * 16, n0 = blockIdx.x * 16;
    const int tx = threadIdx.x & 15, ty = threadIdx.x >> 4;
    s[ty][tx] = src[(size_t)(k0 + ty) * 512 + n0 + tx];
    __syncthreads();
    dst[(size_t)(n0 + ty) * 512 + k0 + tx] = f2b(s[tx][ty]);
}

// ---------------------------------------------------------------------------
// MFMA GEMM, m97-style staging (global_load_lds w=16, unpadded LDS).
// C[128x128] = A[M][512](bf16) x Bt[N][512](bf16 n-major).
// MODE 0: -> q/k/v bf16 (q,k scaled 0.125).  MODE 1: +bias -> fp32 out.
// ---------------------------------------------------------------------------
template <int MODE>
__global__ __launch_bounds__(256) void gemm_mfma(
    const ushort* __restrict__ A, const ushort* __restrict__ Bt,
    ushort* __restrict__ oq, ushort* __restrict__ ok, ushort* __restrict__ ov,
    const float* __restrict__ bias, float* __restrict__ out)
{
    __shared__ ushort As[128 * 32];
    __shared__ ushort Bs[128 * 32];
    const int tid  = threadIdx.x;
    const int rowB = blockIdx.y * 128;
    const int colB = blockIdx.x * 128;
    const int wave = tid >> 6, lane = tid & 63;
    const int wm = wave & 1, wn = wave >> 1;
    const int l15 = lane & 15, quad = lane >> 4;

    f32x4 acc[4][4] = {};

    for (int kt = 0; kt < 512; kt += 32) {
#pragma unroll
        for (int p = 0; p < 2; ++p) {
            const int c = p * 256 + tid;
            const int row = c >> 2, sc = (c & 3) * 8;
            async16(A  + (size_t)(rowB + row) * 512 + kt + sc, &As[c * 8]);
            async16(Bt + (size_t)(colB + row) * 512 + kt + sc, &Bs[c * 8]);
        }
        __syncthreads();

        short8 af[4], bf[4];
#pragma unroll
        for (int mi = 0; mi < 4; ++mi)
            af[mi] = *(const short8*)&As[(wm * 64 + mi * 16 + l15) * 32 + quad * 8];
#pragma unroll
        for (int ni = 0; ni < 4; ++ni)
            bf[ni] = *(const short8*)&Bs[(wn * 64 + ni * 16 + l15) * 32 + quad * 8];
#pragma unroll
        for (int mi = 0; mi < 4; ++mi)
#pragma unroll
            for (int ni = 0; ni < 4; ++ni)
                acc[mi][ni] = __builtin_amdgcn_mfma_f32_16x16x32_bf16(
                    af[mi], bf[ni], acc[mi][ni], 0, 0, 0);
        __syncthreads();
    }

#pragma unroll
    for (int mi = 0; mi < 4; ++mi)
#pragma unroll
        for (int ni = 0; ni < 4; ++ni)
#pragma unroll
            for (int r = 0; r < 4; ++r) {
                const int row = rowB + wm * 64 + mi * 16 + quad * 4 + r;
                const int col = colB + wn * 64 + ni * 16 + l15;
                const float val = acc[mi][ni][r];
                if (MODE == 0) {
                    const int sec = col >> 9, c = col & 511;   // block-uniform
                    ushort* dst = (sec == 0) ? oq : (sec == 1) ? ok : ov;
                    const float s = (sec == 2) ? 1.0f : 0.125f;
                    dst[(size_t)row * HH + c] = f2b(val * s);
                } else {
                    out[(size_t)row * EMB + col] = val + bias[col];
                }
            }
}

// ---------------------------------------------------------------------------
// Blocked sparse attention: one workgroup (4 waves) per (b, h, 64-query blk).
// Local band [q0-64, q0+63] via MFMA QK^T; strided keys qi-64j (j=2..qb) are
// the DIAGONALS of key blocks qb-j -> VALU dots. Softmax fp32. PV via VALU
// (lane = d, P broadcast from LDS). Only 2 barriers: all later LDS traffic
// is same-wave (ds ordering via lgkmcnt).
// ---------------------------------------------------------------------------
__global__ __launch_bounds__(256) void attn_block(
    const ushort* __restrict__ q, const ushort* __restrict__ k,
    const ushort* __restrict__ v, ushort* __restrict__ o)
{
    const int qb = blockIdx.x, h = blockIdx.y, b = blockIdx.z;
    const int q0 = qb * 64;
    const int tid = threadIdx.x, wave = tid >> 6, lane = tid & 63;
    const int l15 = lane & 15, quad = lane >> 4;
    const int nstr = (qb >= 2) ? qb - 1 : 0;     // strided j = 2..qb

    __shared__ union { ushort Qs[64][72]; float ss[32][64]; } r1;  // ss overlays dead Qs
    __shared__ union { ushort Ks[128][72]; float Ps[64][132]; } r2; // Ps overlays dead Ks
    __shared__ ushort Vs[128][72];
    __shared__ float denom[64];

    const size_t bbase = (size_t)(b * NSEQ) * HH + h * HID;   // + row*HH
    const size_t qrow0 = bbase + (size_t)q0 * HH;

    // ---- Phase 1: stage Q (64x64), K/V band (128x64, zero-fill key<0) ----
    {
        const int row = tid >> 2, d0 = (tid & 3) * 16;
        const ushort* g = q + qrow0 + (size_t)row * HH + d0;
        *(short8*)&r1.Qs[row][d0]     = *(const short8*)g;
        *(short8*)&r1.Qs[row][d0 + 8] = *(const short8*)(g + 8);
#pragma unroll
        for (int p = 0; p < 2; ++p) {
            const int c = p * 64 + (tid >> 2);
            const int key = q0 - 64 + c;
            if (key >= 0) {
                const ushort* gk = k + bbase + (size_t)key * HH + d0;
                const ushort* gv = v + bbase + (size_t)key * HH + d0;
                *(short8*)&r2.Ks[c][d0]     = *(const short8*)gk;
                *(short8*)&r2.Ks[c][d0 + 8] = *(const short8*)(gk + 8);
                *(short8*)&Vs[c][d0]        = *(const short8*)gv;
                *(short8*)&Vs[c][d0 + 8]    = *(const short8*)(gv + 8);
            } else {
                short8 z = (short8)0;
                *(short8*)&r2.Ks[c][d0] = z; *(short8*)&r2.Ks[c][d0 + 8] = z;
                *(short8*)&Vs[c][d0]    = z; *(short8*)&Vs[c][d0 + 8]    = z;
            }
        }
    }
    __syncthreads();   // B1

    // ---- Phase 2: QK^T local band via MFMA (wave rows 16w..16w+15) ----
    f32x4 acc[8];
#pragma unroll
    for (int t = 0; t < 8; ++t) acc[t] = (f32x4){0.f, 0.f, 0.f, 0.f};
    {
        const short8 a0 = *(const short8*)&r1.Qs[wave * 16 + l15][quad * 8];
        const short8 a1 = *(const short8*)&r1.Qs[wave * 16 + l15][32 + quad * 8];
#pragma unroll
        for (int t = 0; t < 8; ++t) {
            const short8 b0 = *(const short8*)&r2.Ks[t * 16 + l15][quad * 8];
            const short8 b1 = *(const short8*)&r2.Ks[t * 16 + l15][32 + quad * 8];
            acc[t] = __builtin_amdgcn_mfma_f32_16x16x32_bf16(a0, b0, acc[t], 0, 0, 0);
            acc[t] = __builtin_amdgcn_mfma_f32_16x16x32_bf16(a1, b1, acc[t], 0, 0, 0);
        }
    }

    // ---- Phase 3: hoist Q regs, then strided diagonal scores -> ss ----
    float qf[16];
    const int il  = lane >> 2;            // row within wave's 16
    const int qd  = lane & 3;             // d-chunk
    const int irow = wave * 16 + il;      // row within block
    {
        const short8 c0 = *(const short8*)&r1.Qs[irow][qd * 16];
        const short8 c1 = *(const short8*)&r1.Qs[irow][qd * 16 + 8];
#pragma unroll
        for (int e = 0; e < 8; ++e) { qf[e] = b2fs(c0[e]); qf[8 + e] = b2fs(c1[e]); }
    }
    __syncthreads();   // B2: Qs + Ks now dead -> overlays live

    for (int jj = 0; jj < nstr; ++jj) {
        const int key = q0 - 64 * (jj + 2) + irow;    // >= 0 by construction
        const ushort* gk = k + bbase + (size_t)key * HH + h * 0 + qd * 16;
        const short8 k0 = *(const short8*)gk;
        const short8 k1 = *(const short8*)(gk + 8);
        float s = 0.f;
#pragma unroll
        for (int e = 0; e < 8; ++e) s += qf[e] * b2fs(k0[e]) + qf[8 + e] * b2fs(k1[e]);
        s += __shfl_xor(s, 1); s += __shfl_xor(s, 2);
        if (qd == 0) r1.ss[jj][irow] = s;
    }

    // ---- Phase 4: masked softmax stats (MFMA C layout), exp -> Ps/ss ----
    float mx[4], sm[4];
#pragma unroll
    for (int r = 0; r < 4; ++r) {
        const int i = wave * 16 + quad * 4 + r;
        float m = -1e30f;
#pragma unroll
        for (int t = 0; t < 8; ++t) {
            const int col = t * 16 + l15;
            const bool okm = (col >= i) && (col <= i + 64) && (q0 - 64 + col >= 0);
            const float s = okm ? acc[t][r] : -1e30f;
            acc[t][r] = s;
            m = fmaxf(m, s);
        }
        if (l15 < nstr)      m = fmaxf(m, r1.ss[l15][i]);
        if (l15 + 16 < nstr) m = fmaxf(m, r1.ss[l15 + 16][i]);
        mx[r] = m;
    }
#pragma unroll
    for (int off = 1; off <= 8; off <<= 1)
#pragma unroll
        for (int r = 0; r < 4; ++r) mx[r] = fmaxf(mx[r], __shfl_xor(mx[r], off));
#pragma unroll
    for (int r = 0; r < 4; ++r) {
        const int i = wave * 16 + quad * 4 + r;
        float s = 0.f;
#pragma unroll
        for (int t = 0; t < 8; ++t) {
            const float p = __expf(acc[t][r] - mx[r]);   // masked -> exp(-huge)=0
            r2.Ps[i][t * 16 + l15] = p;
            s += p;
        }
        if (l15 < nstr) {
            const float e = __expf(r1.ss[l15][i] - mx[r]);
            r1.ss[l15][i] = e; s += e;
        }
        if (l15 + 16 < nstr) {
            const float e = __expf(r1.ss[l15 + 16][i] - mx[r]);
            r1.ss[l15 + 16][i] = e; s += e;
        }
        sm[r] = s;
    }
#pragma unroll
    for (int off = 1; off <= 8; off <<= 1)
#pragma unroll
        for (int r = 0; r < 4; ++r) sm[r] += __shfl_xor(sm[r], off);
    if (l15 == 0)
#pragma unroll
        for (int r = 0; r < 4; ++r) denom[wave * 16 + quad * 4 + r] = sm[r];

    // ---- Phase 5: PV (lane = d). All LDS reads are same-wave-produced. ----
    float O[16];
#pragma unroll
    for (int i = 0; i < 16; ++i) O[i] = 0.f;
#pragma unroll 2
    for (int cb = 0; cb < 8; ++cb) {       // local band, 16 keys per step
        float vv[16];
#pragma unroll
        for (int e = 0; e < 16; ++e) vv[e] = b2f(Vs[cb * 16 + e][lane]);
#pragma unroll
        for (int i2 = 0; i2 < 16; ++i2) {
            const float* prow = &r2.Ps[wave * 16 + i2][cb * 16];
            const f32x4 p0 = ((const f32x4*)prow)[0];
            const f32x4 p1 = ((const f32x4*)prow)[1];
            const f32x4 p2 = ((const f32x4*)prow)[2];
            const f32x4 p3 = ((const f32x4*)prow)[3];
            float a = O[i2];
            a += p0.x*vv[0] + p0.y*vv[1] + p0.z*vv[2] + p0.w*vv[3];
            a += p1.x*vv[4] + p1.y*vv[5] + p1.z*vv[6] + p1.w*vv[7];
            a += p2.x*vv[8] + p2.y*vv[9] + p2.z*vv[10] + p2.w*vv[11];
            a += p3.x*vv[12] + p3.y*vv[13] + p3.z*vv[14] + p3.w*vv[15];
            O[i2] = a;
        }
    }
    for (int jj = 0; jj < nstr; ++jj) {    // strided: one V row per (jj, i)
#pragma unroll
        for (int i2 = 0; i2 < 16; ++i2) {
            const int i = wave * 16 + i2;
            const int key = q0 - 64 * (jj + 2) + i;
            const float t = r1.ss[jj][i];                      // broadcast
            O[i2] += t * b2f(v[bbase + (size_t)key * HH + lane]);
        }
    }
#pragma unroll
    for (int i2 = 0; i2 < 16; ++i2) {
        const int i = wave * 16 + i2;
        const float rinv = 1.0f / denom[i];
        o[qrow0 + (size_t)i * HH + lane] = f2b(O[i2] * rinv);
    }
}

// ---------------------------------------------------------------------------
extern "C" void kernel_launch(void* const* d_in, const int* in_sizes, int n_in,
                              void* d_out, int out_size, void* d_ws, size_t ws_size,
                              hipStream_t stream)
{
    // dict order: x, w_keys, w_queries, w_values, w_unify, b_unify (fp32)
    const float* x  = (const float*)d_in[0];
    const float* wk = (const float*)d_in[1];
    const float* wq = (const float*)d_in[2];
    const float* wv = (const float*)d_in[3];
    const float* wu = (const float*)d_in[4];
    const float* bu = (const float*)d_in[5];
    float* out = (float*)d_out;

    // ws (bf16): xb 8MB | wbt 1.5MB | wubt .5MB | ob 8MB | qb 8MB | kb 8MB | vb 8MB
    ushort* xb   = (ushort*)d_ws;
    ushort* wbt  = xb   + (size_t)ROWS * EMB;
    ushort* wubt = wbt  + (size_t)1536 * 512;
    ushort* ob   = wubt + (size_t)512 * 512;
    ushort* qbuf = ob   + (size_t)ROWS * HH;
    ushort* kbuf = qbuf + (size_t)ROWS * HH;
    ushort* vbuf = kbuf + (size_t)ROWS * HH;

    const int n4 = ROWS * EMB / 4;
    f2b_vec<<<(n4 + 255) / 256, 256, 0, stream>>>(x, xb, n4);
    transpose_f2b4<<<dim3(32, 32, 4), 256, 0, stream>>>(wq, wk, wv, wu, wbt, wubt);

    gemm_mfma<0><<<dim3(1536 / 128, ROWS / 128), 256, 0, stream>>>(
        xb, wbt, qbuf, kbuf, vbuf, nullptr, nullptr);
    attn_block<<<dim3(NSEQ / 64, HEADS, BS), 256, 0, stream>>>(qbuf, kbuf, vbuf, ob);
    gemm_mfma<1><<<dim3(EMB / 128, ROWS / 128), 256, 0, stream>>>(
        ob, wubt, nullptr, nullptr, nullptr, bu, out);
}

// Round 6
// 202.516 us; speedup vs baseline: 1.3237x; 1.3237x over previous
//
#include <hip/hip_runtime.h>
#include <hip/hip_bf16.h>

#define HEADS 8
#define HID   64
#define EMB   512
#define HH    512
#define LOCAL 64
#define BS    4
#define NSEQ  2048
#define ROWS  (BS*NSEQ)   // 8192

typedef __attribute__((ext_vector_type(8))) short short8;   // 8 bf16 = 4 VGPRs
typedef __attribute__((ext_vector_type(4))) float f32x4;

__device__ __forceinline__ ushort f2b(float f) {
    union { float f; unsigned u; } c; c.f = f;
    return (ushort)((c.u + 0x7FFFu + ((c.u >> 16) & 1u)) >> 16);
}
__device__ __forceinline__ float b2f(ushort u) {
    union { unsigned u; float f; } c; c.u = ((unsigned)u) << 16; return c.f;
}

__device__ __forceinline__ void async16(const void* g, void* l) {
    __builtin_amdgcn_global_load_lds(
        (const __attribute__((address_space(1))) void*)g,
        (__attribute__((address_space(3))) void*)l, 16, 0, 0);
}

// ---------------------------------------------------------------------------
__global__ __launch_bounds__(256) void f2b_vec(const float* __restrict__ in,
                                               ushort* __restrict__ out, int n4) {
    int i = blockIdx.x * 256 + threadIdx.x;
    if (i >= n4) return;
    float4 f = ((const float4*)in)[i];
    ushort4 u;
    u.x = f2b(f.x); u.y = f2b(f.y); u.z = f2b(f.z); u.w = f2b(f.w);
    ((ushort4*)out)[i] = u;
}

__global__ __launch_bounds__(256) void transpose_f2b4(
    const float* __restrict__ w0, const float* __restrict__ w1,
    const float* __restrict__ w2, const float* __restrict__ w3,
    ushort* __restrict__ dst012, ushort* __restrict__ dst3)
{
    __shared__ float s[16][17];
    const int z = blockIdx.z;
    const float* src = (z == 0) ? w0 : (z == 1) ? w1 : (z == 2) ? w2 : w3;
    ushort* dst = (z < 3) ? dst012 + (size_t)z * 512 * 512 : dst3;
    const int k0 = blockIdx.y * 16, n0 = blockIdx.x * 16;
    const int tx = threadIdx.x & 15, ty = threadIdx.x >> 4;
    s[ty][tx] = src[(size_t)(k0 + ty) * 512 + n0 + tx];
    __syncthreads();
    dst[(size_t)(n0 + ty) * 512 + k0 + tx] = f2b(s[tx][ty]);
}

// ---------------------------------------------------------------------------
// MFMA GEMM (m97-style global_load_lds staging).
// MODE 0: -> q/k/v bf16 (q,k scaled 0.125); v ALSO written transposed to vT.
// MODE 1: +bias -> fp32 out.
// ---------------------------------------------------------------------------
template <int MODE>
__global__ __launch_bounds__(256) void gemm_mfma(
    const ushort* __restrict__ A, const ushort* __restrict__ Bt,
    ushort* __restrict__ oq, ushort* __restrict__ ok, ushort* __restrict__ ov,
    ushort* __restrict__ vT, const float* __restrict__ bias,
    float* __restrict__ out)
{
    __shared__ ushort As[128 * 32];
    __shared__ ushort Bs[128 * 32];
    const int tid  = threadIdx.x;
    const int rowB = blockIdx.y * 128;
    const int colB = blockIdx.x * 128;
    const int wave = tid >> 6, lane = tid & 63;
    const int wm = wave & 1, wn = wave >> 1;
    const int l15 = lane & 15, quad = lane >> 4;

    f32x4 acc[4][4] = {};

    for (int kt = 0; kt < 512; kt += 32) {
#pragma unroll
        for (int p = 0; p < 2; ++p) {
            const int c = p * 256 + tid;
            const int row = c >> 2, sc = (c & 3) * 8;
            async16(A  + (size_t)(rowB + row) * 512 + kt + sc, &As[c * 8]);
            async16(Bt + (size_t)(colB + row) * 512 + kt + sc, &Bs[c * 8]);
        }
        __syncthreads();

        short8 af[4], bf[4];
#pragma unroll
        for (int mi = 0; mi < 4; ++mi)
            af[mi] = *(const short8*)&As[(wm * 64 + mi * 16 + l15) * 32 + quad * 8];
#pragma unroll
        for (int ni = 0; ni < 4; ++ni)
            bf[ni] = *(const short8*)&Bs[(wn * 64 + ni * 16 + l15) * 32 + quad * 8];
#pragma unroll
        for (int mi = 0; mi < 4; ++mi)
#pragma unroll
            for (int ni = 0; ni < 4; ++ni)
                acc[mi][ni] = __builtin_amdgcn_mfma_f32_16x16x32_bf16(
                    af[mi], bf[ni], acc[mi][ni], 0, 0, 0);
        __syncthreads();
    }

#pragma unroll
    for (int mi = 0; mi < 4; ++mi)
#pragma unroll
        for (int ni = 0; ni < 4; ++ni)
#pragma unroll
            for (int r = 0; r < 4; ++r) {
                const int row = rowB + wm * 64 + mi * 16 + quad * 4 + r;
                const int col = colB + wn * 64 + ni * 16 + l15;
                const float val = acc[mi][ni][r];
                if (MODE == 0) {
                    const int sec = col >> 9, c = col & 511;   // block-uniform
                    ushort* dst = (sec == 0) ? oq : (sec == 1) ? ok : ov;
                    const float s = (sec == 2) ? 1.0f : 0.125f;
                    const ushort bv = f2b(val * s);
                    dst[(size_t)row * HH + c] = bv;
                    if (sec == 2) {
                        const int bb = row >> 11, nn = row & 2047;
                        const int hh = c >> 6, dd = c & 63;
                        vT[((size_t)((bb * HEADS + hh) * HID + dd)) * NSEQ + nn] = bv;
                    }
                } else {
                    out[(size_t)row * EMB + col] = val + bias[col];
                }
            }
}

// ---------------------------------------------------------------------------
// Attention v3: barrier-free, one wave per 16 queries. All MFMA operand
// fragments load directly from global (Q/K rows and vT rows are contiguous).
// Local band (80 keys) via MFMA QK^T; strided keys qi-64j (j=2..qb) are the
// DIAGONALS of aligned key tiles -> batched 8-at-a-time as MFMA n-tiles,
// diag extracted to LDS. PV local via MFMA (P bf16 in LDS as A-frags, vT as
// B-frags); strided PV via VALU lane=d. Per-wave LDS, no __syncthreads.
// ---------------------------------------------------------------------------
struct __align__(16) WaveWS {
    union { ushort Ps[16][112]; float Ot[16][66]; } u;  // 4224 B
    float ps_str[32][17];                               // 2176 B
    float rden[16];                                     // 64 B  -> 6464 B
};

__global__ __launch_bounds__(256) void attn_v3(
    const ushort* __restrict__ q, const ushort* __restrict__ k,
    const ushort* __restrict__ v, const ushort* __restrict__ vT,
    ushort* __restrict__ o)
{
    const int qb = (int)(gridDim.x - 1) - (int)blockIdx.x;  // big blocks first
    const int h = blockIdx.y, b = blockIdx.z;
    const int wave = threadIdx.x >> 6, lane = threadIdx.x & 63;
    const int l15 = lane & 15, quad = lane >> 4;
    const int qw = qb * 64 + wave * 16;          // first query row of this wave
    const int nstr = (qb >= 2) ? (qb - 1) : 0;   // strided j = 2..qb
    const int band0 = qw - 64;                   // local band start (may be <0)

    __shared__ WaveWS smem[4];
    WaveWS& S = smem[wave];

    const ptrdiff_t rowb = (ptrdiff_t)b * NSEQ;
    const int hb = h * HID;

    // zero Ps pad columns [80,96): 64 lanes cover 16 rows x 16 cols
    { ushort4 z = {0, 0, 0, 0}; *(ushort4*)&S.u.Ps[l15][80 + quad * 4] = z; }

    // Q A-fragments (2 ksteps over d=64), direct from global
    short8 afq[2];
    {
        const ushort* qp = q + (rowb + qw + l15) * 512 + hb + quad * 8;
        afq[0] = *(const short8*)qp;
        afq[1] = *(const short8*)(qp + 32);
    }

    // ---- local band QK^T: 5 key tiles ----
    f32x4 accL[5];
#pragma unroll
    for (int kt = 0; kt < 5; ++kt) {
        accL[kt] = (f32x4){0.f, 0.f, 0.f, 0.f};
        const ushort* kp = k + (rowb + band0 + kt * 16 + l15) * 512 + hb + quad * 8;
        const short8 b0 = *(const short8*)kp;
        const short8 b1 = *(const short8*)(kp + 32);
        accL[kt] = __builtin_amdgcn_mfma_f32_16x16x32_bf16(afq[0], b0, accL[kt], 0, 0, 0);
        accL[kt] = __builtin_amdgcn_mfma_f32_16x16x32_bf16(afq[1], b1, accL[kt], 0, 0, 0);
    }

    // ---- strided scores: 8 key tiles per MFMA pass, keep only diagonals ----
    const bool isdiag = ((l15 >> 2) == quad);
    const int rr = l15 & 3;
    for (int p = 0; p * 8 < nstr; ++p) {
        f32x4 accS[8];
#pragma unroll
        for (int t = 0; t < 8; ++t) {
            accS[t] = (f32x4){0.f, 0.f, 0.f, 0.f};
            const int jj = p * 8 + t;
            const ushort* kp = k + (rowb + (qw - 64 * (jj + 2)) + l15) * 512 + hb + quad * 8;
            const short8 b0 = *(const short8*)kp;             // may be garbage if jj>=nstr (finite, discarded)
            const short8 b1 = *(const short8*)(kp + 32);
            accS[t] = __builtin_amdgcn_mfma_f32_16x16x32_bf16(afq[0], b0, accS[t], 0, 0, 0);
            accS[t] = __builtin_amdgcn_mfma_f32_16x16x32_bf16(afq[1], b1, accS[t], 0, 0, 0);
        }
        if (isdiag) {   // lane holds diag of row l15 in reg rr
#pragma unroll
            for (int t = 0; t < 8; ++t) {
                const int jj = p * 8 + t;
                const float val = (rr == 0) ? accS[t][0] : (rr == 1) ? accS[t][1]
                                : (rr == 2) ? accS[t][2] : accS[t][3];
                if (jj < nstr) S.ps_str[jj][l15] = val;
            }
        }
    }

    // ---- masked softmax (C-layout rows), P -> LDS bf16 ----
    float rden_r[4];
#pragma unroll
    for (int r = 0; r < 4; ++r) {
        const int row16 = quad * 4 + r;
        float pm[5], mx = -1e30f;
#pragma unroll
        for (int kt = 0; kt < 5; ++kt) {
            const int col = kt * 16 + l15;   // 0..79 within band
            const bool okm = (col >= row16) && (col <= 64 + row16) && (band0 + col >= 0);
            pm[kt] = okm ? accL[kt][r] : -1e30f;
            mx = fmaxf(mx, pm[kt]);
        }
        const float rs0 = (l15 < nstr)      ? S.ps_str[l15][row16]      : -1e30f;
        const float rs1 = (l15 + 16 < nstr) ? S.ps_str[l15 + 16][row16] : -1e30f;
        mx = fmaxf(mx, fmaxf(rs0, rs1));
        mx = fmaxf(mx, __shfl_xor(mx, 1)); mx = fmaxf(mx, __shfl_xor(mx, 2));
        mx = fmaxf(mx, __shfl_xor(mx, 4)); mx = fmaxf(mx, __shfl_xor(mx, 8));
        float sum = 0.f;
#pragma unroll
        for (int kt = 0; kt < 5; ++kt) {
            const float pv = __expf(pm[kt] - mx);
            sum += pv;
            S.u.Ps[row16][kt * 16 + l15] = f2b(pv);
        }
        if (l15 < nstr)      { const float e = __expf(rs0 - mx); S.ps_str[l15][row16] = e;      sum += e; }
        if (l15 + 16 < nstr) { const float e = __expf(rs1 - mx); S.ps_str[l15 + 16][row16] = e; sum += e; }
        sum += __shfl_xor(sum, 1); sum += __shfl_xor(sum, 2);
        sum += __shfl_xor(sum, 4); sum += __shfl_xor(sum, 8);
        rden_r[r] = 1.0f / sum;
        if (l15 == 0) S.rden[row16] = rden_r[r];
    }

    // ---- PV local via MFMA: A = Ps (bf16), B = vT rows (global, contig) ----
    f32x4 O[4];
#pragma unroll
    for (int nt = 0; nt < 4; ++nt) O[nt] = (f32x4){0.f, 0.f, 0.f, 0.f};
    const ushort* vtb = vT + ((ptrdiff_t)(b * HEADS + h) * HID) * NSEQ;
#pragma unroll
    for (int ks = 0; ks < 3; ++ks) {
        const short8 ap = *(const short8*)&S.u.Ps[l15][ks * 32 + quad * 8];
#pragma unroll
        for (int nt = 0; nt < 4; ++nt) {
            const short8 bp = *(const short8*)(
                vtb + (ptrdiff_t)(nt * 16 + l15) * NSEQ + band0 + ks * 32 + quad * 8);
            O[nt] = __builtin_amdgcn_mfma_f32_16x16x32_bf16(ap, bp, O[nt], 0, 0, 0);
        }
    }

    // ---- strided PV: lane = d, p broadcast from LDS ----
    float O2[16];
#pragma unroll
    for (int i2 = 0; i2 < 16; ++i2) O2[i2] = 0.f;
    for (int jj = 0; jj < nstr; ++jj) {
        const ptrdiff_t base = qw - 64 * (jj + 2);
#pragma unroll
        for (int i2 = 0; i2 < 16; ++i2) {
            const float p = S.ps_str[jj][i2];
            O2[i2] += p * b2f(v[(rowb + base + i2) * 512 + hb + lane]);
        }
    }

    // ---- merge (C-layout + lane=d) via LDS, store bf16 ----
#pragma unroll
    for (int nt = 0; nt < 4; ++nt)
#pragma unroll
        for (int r = 0; r < 4; ++r)
            S.u.Ot[quad * 4 + r][nt * 16 + l15] = O[nt][r] * rden_r[r];
#pragma unroll
    for (int i2 = 0; i2 < 16; ++i2) {
        const float val = S.u.Ot[i2][lane] + O2[i2] * S.rden[i2];
        o[(rowb + qw + i2) * 512 + hb + lane] = f2b(val);
    }
}

// ---------------------------------------------------------------------------
extern "C" void kernel_launch(void* const* d_in, const int* in_sizes, int n_in,
                              void* d_out, int out_size, void* d_ws, size_t ws_size,
                              hipStream_t stream)
{
    // dict order: x, w_keys, w_queries, w_values, w_unify, b_unify (fp32)
    const float* x  = (const float*)d_in[0];
    const float* wk = (const float*)d_in[1];
    const float* wq = (const float*)d_in[2];
    const float* wv = (const float*)d_in[3];
    const float* wu = (const float*)d_in[4];
    const float* bu = (const float*)d_in[5];
    float* out = (float*)d_out;

    // ws (bf16): xb 8M | wbt 1.5M | wubt .5M | ob 8M | qb 8M | kb 8M | vT 8M | vb 8M
    // (vT before vb so PV pad-column reads past a vT row stay in-bounds)
    ushort* xb   = (ushort*)d_ws;
    ushort* wbt  = xb   + (size_t)ROWS * EMB;
    ushort* wubt = wbt  + (size_t)1536 * 512;
    ushort* ob   = wubt + (size_t)512 * 512;
    ushort* qbuf = ob   + (size_t)ROWS * HH;
    ushort* kbuf = qbuf + (size_t)ROWS * HH;
    ushort* vTb  = kbuf + (size_t)ROWS * HH;
    ushort* vbuf = vTb  + (size_t)ROWS * HH;

    const int n4 = ROWS * EMB / 4;
    f2b_vec<<<(n4 + 255) / 256, 256, 0, stream>>>(x, xb, n4);
    transpose_f2b4<<<dim3(32, 32, 4), 256, 0, stream>>>(wq, wk, wv, wu, wbt, wubt);

    gemm_mfma<0><<<dim3(1536 / 128, ROWS / 128), 256, 0, stream>>>(
        xb, wbt, qbuf, kbuf, vbuf, vTb, nullptr, nullptr);
    attn_v3<<<dim3(NSEQ / 64, HEADS, BS), 256, 0, stream>>>(qbuf, kbuf, vbuf, vTb, ob);
    gemm_mfma<1><<<dim3(EMB / 128, ROWS / 128), 256, 0, stream>>>(
        ob, wubt, nullptr, nullptr, nullptr, nullptr, bu, out);
}

// Round 7
// 159.901 us; speedup vs baseline: 1.6765x; 1.2665x over previous
//
#include <hip/hip_runtime.h>
#include <hip/hip_bf16.h>

#define HEADS 8
#define HID   64
#define EMB   512
#define HH    512
#define LOCAL 64
#define BS    4
#define NSEQ  2048
#define ROWS  (BS*NSEQ)   // 8192

typedef __attribute__((ext_vector_type(8))) short short8;   // 8 bf16 = 4 VGPRs
typedef __attribute__((ext_vector_type(4))) float f32x4;

__device__ __forceinline__ ushort f2b(float f) {
    union { float f; unsigned u; } c; c.f = f;
    return (ushort)((c.u + 0x7FFFu + ((c.u >> 16) & 1u)) >> 16);
}
__device__ __forceinline__ float b2f(ushort u) {
    union { unsigned u; float f; } c; c.u = ((unsigned)u) << 16; return c.f;
}

__device__ __forceinline__ void async16(const void* g, void* l) {
    __builtin_amdgcn_global_load_lds(
        (const __attribute__((address_space(1))) void*)g,
        (__attribute__((address_space(3))) void*)l, 16, 0, 0);
}

// ---------------------------------------------------------------------------
__global__ __launch_bounds__(256) void f2b_vec(const float* __restrict__ in,
                                               ushort* __restrict__ out, int n4) {
    int i = blockIdx.x * 256 + threadIdx.x;
    if (i >= n4) return;
    float4 f = ((const float4*)in)[i];
    ushort4 u;
    u.x = f2b(f.x); u.y = f2b(f.y); u.z = f2b(f.z); u.w = f2b(f.w);
    ((ushort4*)out)[i] = u;
}

__global__ __launch_bounds__(256) void transpose_f2b4(
    const float* __restrict__ w0, const float* __restrict__ w1,
    const float* __restrict__ w2, const float* __restrict__ w3,
    ushort* __restrict__ dst012, ushort* __restrict__ dst3)
{
    __shared__ float s[16][17];
    const int z = blockIdx.z;
    const float* src = (z == 0) ? w0 : (z == 1) ? w1 : (z == 2) ? w2 : w3;
    ushort* dst = (z < 3) ? dst012 + (size_t)z * 512 * 512 : dst3;
    const int k0 = blockIdx.y * 16, n0 = blockIdx.x * 16;
    const int tx = threadIdx.x & 15, ty = threadIdx.x >> 4;
    s[ty][tx] = src[(size_t)(k0 + ty) * 512 + n0 + tx];
    __syncthreads();
    dst[(size_t)(n0 + ty) * 512 + k0 + tx] = f2b(s[tx][ty]);
}

// v[b*2048+n][h*64+d] -> vT[((b*8+h)*64+d)*2048 + n]; 64x64 tiles via LDS.
__global__ __launch_bounds__(256) void transpose_v(
    const ushort* __restrict__ v, ushort* __restrict__ vT)
{
    __shared__ ushort s[64][65];   // pad 65: transposed read is 2-way (free)
    const int nt = blockIdx.x, h = blockIdx.y, b = blockIdx.z;
    const int tid = threadIdx.x;
    {   // load 64 n-rows x 64 d, 4 threads/row, ushort8 x2 each
        const int n = tid >> 2, d0 = (tid & 3) * 16;
        const ushort* g = v + ((size_t)(b * NSEQ + nt * 64 + n)) * HH + h * HID + d0;
        *(short8*)&s[n][d0]     = *(const short8*)g;
        *(short8*)&s[n][d0 + 8] = *(const short8*)(g + 8);
    }
    __syncthreads();
    {   // write 64 d-rows x 64 n, 4 threads/row (seg), contiguous in n
        const int d = tid & 63, seg = tid >> 6;
        ushort* gout = vT + ((size_t)((b * HEADS + h) * HID + d)) * NSEQ + nt * 64 + seg * 16;
#pragma unroll
        for (int j = 0; j < 16; ++j) gout[j] = s[seg * 16 + j][d];
    }
}

// ---------------------------------------------------------------------------
// MFMA GEMM (m97-style staging).  1-D grid, lin = col*64 + row so all blocks
// sharing an A-stripe have the same lin%8 -> same XCD -> A served from L2.
// MODE 0: -> q/k/v bf16 (q,k scaled 0.125).  MODE 1: +bias -> fp32 out.
// ---------------------------------------------------------------------------
template <int MODE>
__global__ __launch_bounds__(256) void gemm_mfma(
    const ushort* __restrict__ A, const ushort* __restrict__ Bt,
    ushort* __restrict__ oq, ushort* __restrict__ ok, ushort* __restrict__ ov,
    const float* __restrict__ bias, float* __restrict__ out)
{
    __shared__ ushort As[128 * 32];
    __shared__ ushort Bs[128 * 32];
    const int tid  = threadIdx.x;
    const int rowB = (blockIdx.x & 63) * 128;   // 64 row-blocks (M=8192)
    const int colB = (blockIdx.x >> 6) * 128;
    const int wave = tid >> 6, lane = tid & 63;
    const int wm = wave & 1, wn = wave >> 1;
    const int l15 = lane & 15, quad = lane >> 4;

    f32x4 acc[4][4] = {};

    for (int kt = 0; kt < 512; kt += 32) {
#pragma unroll
        for (int p = 0; p < 2; ++p) {
            const int c = p * 256 + tid;
            const int row = c >> 2, sc = (c & 3) * 8;
            async16(A  + (size_t)(rowB + row) * 512 + kt + sc, &As[c * 8]);
            async16(Bt + (size_t)(colB + row) * 512 + kt + sc, &Bs[c * 8]);
        }
        __syncthreads();

        short8 af[4], bf[4];
#pragma unroll
        for (int mi = 0; mi < 4; ++mi)
            af[mi] = *(const short8*)&As[(wm * 64 + mi * 16 + l15) * 32 + quad * 8];
#pragma unroll
        for (int ni = 0; ni < 4; ++ni)
            bf[ni] = *(const short8*)&Bs[(wn * 64 + ni * 16 + l15) * 32 + quad * 8];
#pragma unroll
        for (int mi = 0; mi < 4; ++mi)
#pragma unroll
            for (int ni = 0; ni < 4; ++ni)
                acc[mi][ni] = __builtin_amdgcn_mfma_f32_16x16x32_bf16(
                    af[mi], bf[ni], acc[mi][ni], 0, 0, 0);
        __syncthreads();
    }

#pragma unroll
    for (int mi = 0; mi < 4; ++mi)
#pragma unroll
        for (int ni = 0; ni < 4; ++ni)
#pragma unroll
            for (int r = 0; r < 4; ++r) {
                const int row = rowB + wm * 64 + mi * 16 + quad * 4 + r;
                const int col = colB + wn * 64 + ni * 16 + l15;
                const float val = acc[mi][ni][r];
                if (MODE == 0) {
                    const int sec = col >> 9, c = col & 511;   // block-uniform
                    ushort* dst = (sec == 0) ? oq : (sec == 1) ? ok : ov;
                    const float s = (sec == 2) ? 1.0f : 0.125f;
                    dst[(size_t)row * HH + c] = f2b(val * s);
                } else {
                    out[(size_t)row * EMB + col] = val + bias[col];
                }
            }
}

// ---------------------------------------------------------------------------
// Attention v3 + XCD swizzle: 1-D grid, lin = qb'*32 + (h + 8b) so all query
// blocks of one (b,h) slice share lin%8 -> same XCD -> strided K/V re-reads
// hit L2.  qb reversed (heavy blocks dispatch first).  Barrier-free waves.
// ---------------------------------------------------------------------------
struct __align__(16) WaveWS {
    union { ushort Ps[16][112]; float Ot[16][66]; } u;  // 4224 B
    float ps_str[32][17];                               // 2176 B
    float rden[16];                                     // 64 B  -> 6464 B
};

__global__ __launch_bounds__(256) void attn_v3(
    const ushort* __restrict__ q, const ushort* __restrict__ k,
    const ushort* __restrict__ v, const ushort* __restrict__ vT,
    ushort* __restrict__ o)
{
    const int slice = blockIdx.x & 31;           // h + 8*b
    const int qb    = 31 - (blockIdx.x >> 5);    // heavy first
    const int h = slice & 7, b = slice >> 3;
    const int wave = threadIdx.x >> 6, lane = threadIdx.x & 63;
    const int l15 = lane & 15, quad = lane >> 4;
    const int qw = qb * 64 + wave * 16;
    const int nstr = (qb >= 2) ? (qb - 1) : 0;   // strided j = 2..qb
    const int band0 = qw - 64;

    __shared__ WaveWS smem[4];
    WaveWS& S = smem[wave];

    const ptrdiff_t rowb = (ptrdiff_t)b * NSEQ;
    const int hb = h * HID;

    // zero Ps pad columns [80,96)
    { ushort4 z = {0, 0, 0, 0}; *(ushort4*)&S.u.Ps[l15][80 + quad * 4] = z; }

    // Q A-fragments direct from global
    short8 afq[2];
    {
        const ushort* qp = q + (rowb + qw + l15) * 512 + hb + quad * 8;
        afq[0] = *(const short8*)qp;
        afq[1] = *(const short8*)(qp + 32);
    }

    // ---- local band QK^T: 5 key tiles ----
    f32x4 accL[5];
#pragma unroll
    for (int kt = 0; kt < 5; ++kt) {
        accL[kt] = (f32x4){0.f, 0.f, 0.f, 0.f};
        const ushort* kp = k + (rowb + band0 + kt * 16 + l15) * 512 + hb + quad * 8;
        const short8 b0 = *(const short8*)kp;
        const short8 b1 = *(const short8*)(kp + 32);
        accL[kt] = __builtin_amdgcn_mfma_f32_16x16x32_bf16(afq[0], b0, accL[kt], 0, 0, 0);
        accL[kt] = __builtin_amdgcn_mfma_f32_16x16x32_bf16(afq[1], b1, accL[kt], 0, 0, 0);
    }

    // ---- strided scores: 8 key tiles per MFMA pass, keep diagonals ----
    const bool isdiag = ((l15 >> 2) == quad);
    const int rr = l15 & 3;
    for (int p = 0; p * 8 < nstr; ++p) {
        f32x4 accS[8];
#pragma unroll
        for (int t = 0; t < 8; ++t) {
            accS[t] = (f32x4){0.f, 0.f, 0.f, 0.f};
            const int jj = p * 8 + t;
            const ushort* kp = k + (rowb + (qw - 64 * (jj + 2)) + l15) * 512 + hb + quad * 8;
            const short8 b0 = *(const short8*)kp;   // garbage if jj>=nstr (finite, discarded)
            const short8 b1 = *(const short8*)(kp + 32);
            accS[t] = __builtin_amdgcn_mfma_f32_16x16x32_bf16(afq[0], b0, accS[t], 0, 0, 0);
            accS[t] = __builtin_amdgcn_mfma_f32_16x16x32_bf16(afq[1], b1, accS[t], 0, 0, 0);
        }
        if (isdiag) {
#pragma unroll
            for (int t = 0; t < 8; ++t) {
                const int jj = p * 8 + t;
                const float val = (rr == 0) ? accS[t][0] : (rr == 1) ? accS[t][1]
                                : (rr == 2) ? accS[t][2] : accS[t][3];
                if (jj < nstr) S.ps_str[jj][l15] = val;
            }
        }
    }

    // ---- masked softmax (C-layout rows), P -> LDS bf16 ----
    float rden_r[4];
#pragma unroll
    for (int r = 0; r < 4; ++r) {
        const int row16 = quad * 4 + r;
        float pm[5], mx = -1e30f;
#pragma unroll
        for (int kt = 0; kt < 5; ++kt) {
            const int col = kt * 16 + l15;
            const bool okm = (col >= row16) && (col <= 64 + row16) && (band0 + col >= 0);
            pm[kt] = okm ? accL[kt][r] : -1e30f;
            mx = fmaxf(mx, pm[kt]);
        }
        const float rs0 = (l15 < nstr)      ? S.ps_str[l15][row16]      : -1e30f;
        const float rs1 = (l15 + 16 < nstr) ? S.ps_str[l15 + 16][row16] : -1e30f;
        mx = fmaxf(mx, fmaxf(rs0, rs1));
        mx = fmaxf(mx, __shfl_xor(mx, 1)); mx = fmaxf(mx, __shfl_xor(mx, 2));
        mx = fmaxf(mx, __shfl_xor(mx, 4)); mx = fmaxf(mx, __shfl_xor(mx, 8));
        float sum = 0.f;
#pragma unroll
        for (int kt = 0; kt < 5; ++kt) {
            const float pv = __expf(pm[kt] - mx);
            sum += pv;
            S.u.Ps[row16][kt * 16 + l15] = f2b(pv);
        }
        if (l15 < nstr)      { const float e = __expf(rs0 - mx); S.ps_str[l15][row16] = e;      sum += e; }
        if (l15 + 16 < nstr) { const float e = __expf(rs1 - mx); S.ps_str[l15 + 16][row16] = e; sum += e; }
        sum += __shfl_xor(sum, 1); sum += __shfl_xor(sum, 2);
        sum += __shfl_xor(sum, 4); sum += __shfl_xor(sum, 8);
        rden_r[r] = 1.0f / sum;
        if (l15 == 0) S.rden[row16] = rden_r[r];
    }

    // ---- PV local via MFMA: A = Ps (bf16), B = vT rows (global, contig) ----
    f32x4 O[4];
#pragma unroll
    for (int nt = 0; nt < 4; ++nt) O[nt] = (f32x4){0.f, 0.f, 0.f, 0.f};
    const ushort* vtb = vT + ((ptrdiff_t)(b * HEADS + h) * HID) * NSEQ;
#pragma unroll
    for (int ks = 0; ks < 3; ++ks) {
        const short8 ap = *(const short8*)&S.u.Ps[l15][ks * 32 + quad * 8];
#pragma unroll
        for (int nt = 0; nt < 4; ++nt) {
            const short8 bp = *(const short8*)(
                vtb + (ptrdiff_t)(nt * 16 + l15) * NSEQ + band0 + ks * 32 + quad * 8);
            O[nt] = __builtin_amdgcn_mfma_f32_16x16x32_bf16(ap, bp, O[nt], 0, 0, 0);
        }
    }

    // ---- strided PV: lane = d, p broadcast from LDS ----
    float O2[16];
#pragma unroll
    for (int i2 = 0; i2 < 16; ++i2) O2[i2] = 0.f;
    for (int jj = 0; jj < nstr; ++jj) {
        const ptrdiff_t base = qw - 64 * (jj + 2);
#pragma unroll
        for (int i2 = 0; i2 < 16; ++i2) {
            const float p = S.ps_str[jj][i2];
            O2[i2] += p * b2f(v[(rowb + base + i2) * 512 + hb + lane]);
        }
    }

    // ---- merge (C-layout + lane=d) via LDS, store bf16 ----
#pragma unroll
    for (int nt = 0; nt < 4; ++nt)
#pragma unroll
        for (int r = 0; r < 4; ++r)
            S.u.Ot[quad * 4 + r][nt * 16 + l15] = O[nt][r] * rden_r[r];
#pragma unroll
    for (int i2 = 0; i2 < 16; ++i2) {
        const float val = S.u.Ot[i2][lane] + O2[i2] * S.rden[i2];
        o[(rowb + qw + i2) * 512 + hb + lane] = f2b(val);
    }
}

// ---------------------------------------------------------------------------
extern "C" void kernel_launch(void* const* d_in, const int* in_sizes, int n_in,
                              void* d_out, int out_size, void* d_ws, size_t ws_size,
                              hipStream_t stream)
{
    // dict order: x, w_keys, w_queries, w_values, w_unify, b_unify (fp32)
    const float* x  = (const float*)d_in[0];
    const float* wk = (const float*)d_in[1];
    const float* wq = (const float*)d_in[2];
    const float* wv = (const float*)d_in[3];
    const float* wu = (const float*)d_in[4];
    const float* bu = (const float*)d_in[5];
    float* out = (float*)d_out;

    // ws (bf16): xb 8M | wbt 1.5M | wubt .5M | ob 8M | qb 8M | kb 8M | vT 8M | vb 8M
    ushort* xb   = (ushort*)d_ws;
    ushort* wbt  = xb   + (size_t)ROWS * EMB;
    ushort* wubt = wbt  + (size_t)1536 * 512;
    ushort* ob   = wubt + (size_t)512 * 512;
    ushort* qbuf = ob   + (size_t)ROWS * HH;
    ushort* kbuf = qbuf + (size_t)ROWS * HH;
    ushort* vTb  = kbuf + (size_t)ROWS * HH;
    ushort* vbuf = vTb  + (size_t)ROWS * HH;

    const int n4 = ROWS * EMB / 4;
    f2b_vec<<<(n4 + 255) / 256, 256, 0, stream>>>(x, xb, n4);
    transpose_f2b4<<<dim3(32, 32, 4), 256, 0, stream>>>(wq, wk, wv, wu, wbt, wubt);

    gemm_mfma<0><<<12 * 64, 256, 0, stream>>>(xb, wbt, qbuf, kbuf, vbuf,
                                              nullptr, nullptr);
    transpose_v<<<dim3(NSEQ / 64, HEADS, BS), 256, 0, stream>>>(vbuf, vTb);
    attn_v3<<<32 * 32, 256, 0, stream>>>(qbuf, kbuf, vbuf, vTb, ob);
    gemm_mfma<1><<<4 * 64, 256, 0, stream>>>(ob, wubt, nullptr, nullptr, nullptr,
                                             bu, out);
}